// Round 1
// baseline (2290.072 us; speedup 1.0000x reference)
//
#include <hip/hip_runtime.h>

// Problem constants
#define EPS_   1e-4f
#define SCALE_ 0.125f

// ws float offsets
#define OFF_REL   0          // 1025*512 = 524800
#define OFF_H0    524800     // 64*512
#define OFF_H1    557568     // 64*512
#define OFF_XBUF  590336     // 64*512
#define OFF_QK    623104     // 64*8*512 = 262144
#define OFF_QR    885248     // 262144
#define OFF_Y     1147392    // 64*512 (tok, then y per layer)
#define OFF_RSX   1180160    // 64
#define OFF_ML    1180224    // 64*8*8*2 = 8192
#define OFF_SP    1188416    // 64*8*8*512 = 2097152
#define OFF_GP    3285568    // 8*64*2048 = 1048576
#define OFF_FP    4334144    // 32*64*512 = 1048576
// total floats: 5382720  (~21.5 MB of ws)

// d_out float offsets
#define OUT_CACHE 524288
#define OUT_SUMM  201850880

__device__ __forceinline__ float dot4(float4 a, float4 b) {
  return a.x*b.x + a.y*b.y + a.z*b.z + a.w*b.w;
}

__device__ __forceinline__ float blockSum256(float v, float* scr) {
  int t = threadIdx.x;
  scr[t] = v;
  __syncthreads();
  if (t < 128) scr[t] += scr[t + 128];
  __syncthreads();
  if (t < 64) scr[t] += scr[t + 64];
  __syncthreads();
  if (t < 64) {
    float x = scr[t];
    x += __shfl_xor(x, 32); x += __shfl_xor(x, 16); x += __shfl_xor(x, 8);
    x += __shfl_xor(x, 4);  x += __shfl_xor(x, 2);  x += __shfl_xor(x, 1);
    if (t == 0) scr[0] = x;
  }
  __syncthreads();
  float r = scr[0];
  __syncthreads();
  return r;
}

// ---------------- prologue ----------------

// rel[k][e] = sin/cos((1024-k) * invf), already flipped
__global__ __launch_bounds__(256) void k_rel(float* __restrict__ ws) {
  int idx = blockIdx.x*256 + threadIdx.x;
  if (idx >= 1025*512) return;
  int k = idx >> 9, e = idx & 511;
  float p = (float)(1024 - k);
  int j = e & 255;
  float invf = expf(-0.035977892078031965f * (float)j);  // -ln(10000)/256
  float s = p * invf;
  ws[OFF_REL + idx] = (e < 256) ? sinf(s) : cosf(s);
}

// tok = concat(stoch, action_norm) @ in_w.T + in_b   -> ws[OFF_Y]
__global__ __launch_bounds__(256) void k_tok(const float* __restrict__ stoch,
    const float* __restrict__ action, const float* __restrict__ in_w,
    const float* __restrict__ in_b, float* __restrict__ ws) {
  __shared__ float cat[1088];
  __shared__ float scr[256];
  int t = threadIdx.x, dc = blockIdx.x, b = blockIdx.y;
  for (int i = t; i < 1024; i += 256) cat[i] = stoch[b*1024 + i];
  if (t < 64) { float a = action[b*64 + t]; cat[1024 + t] = a / fmaxf(fabsf(a), 1.0f); }
  __syncthreads();
  int dl = t >> 1, half = t & 1;
  int d = dc*128 + dl;
  const float* wrow = in_w + (size_t)d*1088 + half*544;
  const float* crow = cat + half*544;
  float acc = 0.f;
  for (int j = 0; j < 544; j += 4) {
    float4 w = *(const float4*)(wrow + j);
    float4 cv = *(const float4*)(crow + j);
    acc += dot4(w, cv);
  }
  scr[t] = acc;
  __syncthreads();
  if (t < 128)
    ws[OFF_Y + b*512 + dc*128 + t] = scr[2*t] + scr[2*t + 1] + in_b[dc*128 + t];
}

// x0 = silu(rmsnorm(tok, in_norm_w)) -> hbuf0
__global__ __launch_bounds__(256) void k_x0(const float* __restrict__ inorm, float* __restrict__ ws) {
  __shared__ float scr[256];
  int t = threadIdx.x, b = blockIdx.x;
  float t0 = ws[OFF_Y + b*512 + t], t1 = ws[OFF_Y + b*512 + 256 + t];
  float ss = blockSum256(t0*t0 + t1*t1, scr);
  float rs = rsqrtf(ss*(1.0f/512.0f) + EPS_);
  float z0 = t0*rs*inorm[t], z1 = t1*rs*inorm[256 + t];
  ws[OFF_H0 + b*512 + t]       = z0/(1.0f + expf(-z0));
  ws[OFF_H0 + b*512 + 256 + t] = z1/(1.0f + expf(-z1));
}

// ---------------- per-layer: prep (x, Q, qk', qr) ----------------
// grid (h=8, bp=32), 256 thr. Each block handles 2 batches for one head.
__global__ __launch_bounds__(256) void k_prep(int l,
    const float* __restrict__ wq, const float* __restrict__ wk, const float* __restrict__ wr,
    const float* __restrict__ uu, const float* __restrict__ vv,
    const float* __restrict__ n1w, const float* __restrict__ ff_b2,
    float* __restrict__ ws, float* __restrict__ out) {
  __shared__ float xn[2][512];
  __shared__ float Qu[2][64], Qv[2][64];
  __shared__ float scr[256];
  __shared__ float scrQ[64][4][2];
  int t = threadIdx.x;
  int h = blockIdx.x, bp = blockIdx.y;
  const float* hprev = ws + ((l & 1) ? OFF_H1 : OFF_H0);
  float* hcur = ws + ((l & 1) ? OFF_H0 : OFF_H1);
  for (int bb = 0; bb < 2; bb++) {
    int b = bp*2 + bb;
    float x0 = hprev[b*512 + t];
    float x1 = hprev[b*512 + 256 + t];
    if (l > 0) {
      x0 += ff_b2[(l-1)*512 + t];
      x1 += ff_b2[(l-1)*512 + 256 + t];
      for (int fc = 0; fc < 32; fc++) {
        x0 += ws[OFF_FP + fc*32768 + b*512 + t];
        x1 += ws[OFF_FP + fc*32768 + b*512 + 256 + t];
      }
    }
    float ss = blockSum256(x0*x0 + x1*x1, scr);
    float rs = rsqrtf(ss*(1.0f/512.0f) + EPS_);
    xn[bb][t]       = x0*rs*n1w[l*512 + t];
    xn[bb][256 + t] = x1*rs*n1w[l*512 + 256 + t];
    if (h == 0) {
      ws[OFF_XBUF + b*512 + t] = x0;
      ws[OFF_XBUF + b*512 + 256 + t] = x1;
      hcur[b*512 + t] = x0;              // residual base for h = x + attn_out
      hcur[b*512 + 256 + t] = x1;
      size_t cb = (size_t)OUT_CACHE + ((size_t)((l*64 + b)*1024 + 1023))*512;
      out[cb + t] = x0; out[cb + 256 + t] = x1;   // new_cache last row = x
      if (t == 0) ws[OFF_RSX + b] = rs;
    }
  }
  __syncthreads();
  // Q[h,d] for both batches
  int d = t & 63, q = t >> 6;
  {
    const float* wqp = wq + (size_t)l*262144 + (size_t)(h*64 + d)*512 + q*128;
    float a0 = 0.f, a1 = 0.f;
    for (int e = 0; e < 128; e += 4) {
      float4 w = *(const float4*)(wqp + e);
      float4 xa = *(const float4*)(&xn[0][q*128 + e]);
      float4 xb = *(const float4*)(&xn[1][q*128 + e]);
      a0 += dot4(w, xa); a1 += dot4(w, xb);
    }
    scrQ[d][q][0] = a0; scrQ[d][q][1] = a1;
  }
  __syncthreads();
  if (t < 64) {
    float Q0 = scrQ[t][0][0] + scrQ[t][1][0] + scrQ[t][2][0] + scrQ[t][3][0];
    float Q1 = scrQ[t][0][1] + scrQ[t][1][1] + scrQ[t][2][1] + scrQ[t][3][1];
    float uvl = uu[(l*8 + h)*64 + t];
    float vvl = vv[(l*8 + h)*64 + t];
    Qu[0][t] = Q0 + uvl; Qv[0][t] = Q0 + vvl;
    Qu[1][t] = Q1 + uvl; Qv[1][t] = Q1 + vvl;
  }
  __syncthreads();
  // qk'[e] = (sum_d Qu[d]*wk[h*64+d][e]) * n1w[e];  qr[e] = sum_d Qv[d]*wr[h*64+d][e]
  int e0 = t*2;
  const float* wkp = wk + (size_t)l*262144 + (size_t)(h*64)*512 + e0;
  const float* wrp = wr + (size_t)l*262144 + (size_t)(h*64)*512 + e0;
  float K00=0,K01=0,K10=0,K11=0, R00=0,R01=0,R10=0,R11=0;
  for (int dd = 0; dd < 64; dd++) {
    float2 wkv = *(const float2*)(wkp + (size_t)dd*512);
    float2 wrv = *(const float2*)(wrp + (size_t)dd*512);
    float qu0 = Qu[0][dd], qu1 = Qu[1][dd];
    float qv0 = Qv[0][dd], qv1 = Qv[1][dd];
    K00 += qu0*wkv.x; K01 += qu0*wkv.y;
    K10 += qu1*wkv.x; K11 += qu1*wkv.y;
    R00 += qv0*wrv.x; R01 += qv0*wrv.y;
    R10 += qv1*wrv.x; R11 += qv1*wrv.y;
  }
  int b0 = bp*2, b1 = b0 + 1;
  float n0 = n1w[l*512 + e0], n1v = n1w[l*512 + e0 + 1];
  *(float2*)(ws + OFF_QK + (b0*8 + h)*512 + e0) = make_float2(K00*n0, K01*n1v);
  *(float2*)(ws + OFF_QK + (b1*8 + h)*512 + e0) = make_float2(K10*n0, K11*n1v);
  *(float2*)(ws + OFF_QR + (b0*8 + h)*512 + e0) = make_float2(R00, R01);
  *(float2*)(ws + OFF_QR + (b1*8 + h)*512 + e0) = make_float2(R10, R11);
}

// ---------------- per-layer: heavy streaming attention ----------------
// grid (c=8, b=64), 256 thr; 128 cache rows per block.
__global__ __launch_bounds__(256, 2) void k_attn(int l,
    const float* __restrict__ cache, float* __restrict__ ws, float* __restrict__ out) {
  __shared__ float qkL[4096], qrL[4096];
  __shared__ float scr[128*35];
  __shared__ float warr[128*8];
  __shared__ float redm[2][8], redl[2][8];
  int t = threadIdx.x;
  int c = blockIdx.x, b = blockIdx.y;
  for (int i = t*4; i < 4096; i += 1024) {
    *(float4*)(qkL + i) = *(const float4*)(ws + OFF_QK + b*4096 + i);
    *(float4*)(qrL + i) = *(const float4*)(ws + OFF_QR + b*4096 + i);
  }
  __syncthreads();
  // phase 1: per-lane-per-row logits (half-row per lane)
  int r = t & 127, hf = t >> 7;
  int k = c*128 + r;
  const float* crow = cache + ((size_t)((l*64 + b)*1024 + k))*512 + hf*256;
  const float* rrow = ws + OFF_REL + (size_t)k*512 + hf*256;
  const float* qkh = qkL + hf*256;
  const float* qrh = qrL + hf*256;
  float ss = 0.f;
  float dAC[8] = {0,0,0,0,0,0,0,0};
  float dBD[8] = {0,0,0,0,0,0,0,0};
  for (int e = 0; e < 256; e += 8) {
    float4 c0 = *(const float4*)(crow + e);
    float4 c1 = *(const float4*)(crow + e + 4);
    float4 r0 = *(const float4*)(rrow + e);
    float4 r1 = *(const float4*)(rrow + e + 4);
    ss += dot4(c0, c0) + dot4(c1, c1);
    #pragma unroll
    for (int h = 0; h < 8; h++) {
      dAC[h] += dot4(c0, *(const float4*)(qkh + h*512 + e))
              + dot4(c1, *(const float4*)(qkh + h*512 + e + 4));
      dBD[h] += dot4(r0, *(const float4*)(qrh + h*512 + e))
              + dot4(r1, *(const float4*)(qrh + h*512 + e + 4));
    }
  }
  {
    float* s = scr + r*35 + hf*17;
    s[0] = ss;
    #pragma unroll
    for (int h = 0; h < 8; h++) { s[1+h] = dAC[h]; s[9+h] = dBD[h]; }
  }
  __syncthreads();
  bool act = (t < 128);
  int wid = t >> 6, lane = t & 63;
  float z[8], rsq = 0.f;
  if (act) {
    const float* s0 = scr + t*35;
    const float* s1 = s0 + 17;
    rsq = rsqrtf((s0[0] + s1[0])*(1.0f/512.0f) + EPS_);
    #pragma unroll
    for (int h = 0; h < 8; h++)
      z[h] = SCALE_*(rsq*(s0[1+h] + s1[1+h]) + (s0[9+h] + s1[9+h]));
  } else {
    #pragma unroll
    for (int h = 0; h < 8; h++) z[h] = -1e30f;
  }
  #pragma unroll
  for (int h = 0; h < 8; h++) {
    float mw = z[h];
    mw = fmaxf(mw, __shfl_xor(mw, 32)); mw = fmaxf(mw, __shfl_xor(mw, 16));
    mw = fmaxf(mw, __shfl_xor(mw, 8));  mw = fmaxf(mw, __shfl_xor(mw, 4));
    mw = fmaxf(mw, __shfl_xor(mw, 2));  mw = fmaxf(mw, __shfl_xor(mw, 1));
    if (act && lane == 0) redm[wid][h] = mw;
  }
  __syncthreads();
  float m[8], p[8];
  #pragma unroll
  for (int h = 0; h < 8; h++) {
    m[h] = fmaxf(redm[0][h], redm[1][h]);
    p[h] = __expf(z[h] - m[h]);
  }
  #pragma unroll
  for (int h = 0; h < 8; h++) {
    float lw = p[h];
    lw += __shfl_xor(lw, 32); lw += __shfl_xor(lw, 16); lw += __shfl_xor(lw, 8);
    lw += __shfl_xor(lw, 4);  lw += __shfl_xor(lw, 2);  lw += __shfl_xor(lw, 1);
    if (act && lane == 0) redl[wid][h] = lw;
  }
  __syncthreads();
  if (act) {
    #pragma unroll
    for (int h = 0; h < 8; h++) warr[t*8 + h] = p[h]*rsq;
  }
  if (t == 0) {
    #pragma unroll
    for (int h = 0; h < 8; h++) {
      int mlb = OFF_ML + ((b*8 + c)*8 + h)*2;
      ws[mlb] = m[h];
      ws[mlb + 1] = redl[0][h] + redl[1][h];
    }
  }
  __syncthreads();
  // phase 2: coalesced weighted-sum + fused shifted-cache copy
  int e2 = t*2;
  float2 acc[8];
  #pragma unroll
  for (int h = 0; h < 8; h++) acc[h] = make_float2(0.f, 0.f);
  const float* crow2 = cache + ((size_t)((l*64 + b)*1024 + c*128))*512 + e2;
  float* orow = out + (long)OUT_CACHE + ((long)((l*64 + b)*1024 + c*128) - 1)*512 + e2;
  int kglob0 = c*128;
  for (int kk = 0; kk < 128; kk++) {
    float4 w0 = *(const float4*)(warr + kk*8);
    float4 w1 = *(const float4*)(warr + kk*8 + 4);
    float2 rv = *(const float2*)(crow2 + (size_t)kk*512);
    acc[0].x += w0.x*rv.x; acc[0].y += w0.x*rv.y;
    acc[1].x += w0.y*rv.x; acc[1].y += w0.y*rv.y;
    acc[2].x += w0.z*rv.x; acc[2].y += w0.z*rv.y;
    acc[3].x += w0.w*rv.x; acc[3].y += w0.w*rv.y;
    acc[4].x += w1.x*rv.x; acc[4].y += w1.x*rv.y;
    acc[5].x += w1.y*rv.x; acc[5].y += w1.y*rv.y;
    acc[6].x += w1.z*rv.x; acc[6].y += w1.z*rv.y;
    acc[7].x += w1.w*rv.x; acc[7].y += w1.w*rv.y;
    if (kglob0 + kk > 0) *(float2*)(orow + (long)kk*512) = rv;
  }
  #pragma unroll
  for (int h = 0; h < 8; h++)
    *(float2*)(ws + OFF_SP + ((size_t)((b*8 + c)*8 + h))*512 + e2) = acc[h];
}

// ---------------- per-layer: combine softmax partials + attn out ----------------
// grid (h=8, b=64)
__global__ __launch_bounds__(256) void k_ctx(int l,
    const float* __restrict__ wv, const float* __restrict__ wo,
    const float* __restrict__ n1w, float* __restrict__ ws) {
  __shared__ float ctx[512];
  __shared__ float scr[256];
  __shared__ float oL[64];
  __shared__ float scrO[64][4];
  int t = threadIdx.x;
  int h = blockIdx.x, b = blockIdx.y;
  const float* qk = ws + OFF_QK + (b*8 + h)*512;
  const float* qr = ws + OFF_QR + (b*8 + h)*512;
  const float* xb = ws + OFF_XBUF + b*512;
  int e0 = t*2;
  float dx = xb[e0]*qk[e0] + xb[e0+1]*qk[e0+1];
  const float* rl = ws + OFF_REL + 1024*512;
  float bdp = rl[e0]*qr[e0] + rl[e0+1]*qr[e0+1];
  float dotx = blockSum256(dx, scr);
  float bdx = blockSum256(bdp, scr);
  float rsx = ws[OFF_RSX + b];
  float zx = SCALE_*(rsx*dotx + bdx);     // logit of the appended token (k=1024)
  float mc[8], lc[8];
  float M = zx;
  #pragma unroll
  for (int cc = 0; cc < 8; cc++) {
    int mlb = OFF_ML + ((b*8 + cc)*8 + h)*2;
    mc[cc] = ws[mlb]; lc[cc] = ws[mlb + 1];
    M = fmaxf(M, mc[cc]);
  }
  float px = expf(zx - M);
  float Ls = px;
  float ecf[8];
  #pragma unroll
  for (int cc = 0; cc < 8; cc++) { ecf[cc] = expf(mc[cc] - M); Ls += lc[cc]*ecf[cc]; }
  float s0 = px*rsx*xb[e0], s1 = px*rsx*xb[e0+1];
  #pragma unroll
  for (int cc = 0; cc < 8; cc++) {
    const float* sp = ws + OFF_SP + ((size_t)((b*8 + cc)*8 + h))*512;
    s0 += ecf[cc]*sp[e0]; s1 += ecf[cc]*sp[e0+1];
  }
  float inv = 1.0f/Ls;
  ctx[e0]     = s0*inv*n1w[l*512 + e0];
  ctx[e0 + 1] = s1*inv*n1w[l*512 + e0 + 1];
  __syncthreads();
  // o[d] = sum_e ctx[e]*wv[h*64+d][e]
  int d = t & 63, q = t >> 6;
  {
    const float* wvp = wv + (size_t)l*262144 + (size_t)(h*64 + d)*512 + q*128;
    float oa = 0.f;
    for (int e = 0; e < 128; e += 4)
      oa += dot4(*(const float4*)(wvp + e), *(const float4*)(&ctx[q*128 + e]));
    scrO[d][q] = oa;
  }
  __syncthreads();
  if (t < 64) oL[t] = scrO[t][0] + scrO[t][1] + scrO[t][2] + scrO[t][3];
  __syncthreads();
  // out_proj partial for this head -> atomic into hcur (pre-initialized to x)
  float a0 = 0.f, a1 = 0.f;
  const float* wop = wo + (size_t)l*262144 + h*64;
  for (int dd = 0; dd < 64; dd += 4) {
    float4 ov = *(const float4*)(oL + dd);
    a0 += dot4(ov, *(const float4*)(wop + (size_t)t*512 + dd));
    a1 += dot4(ov, *(const float4*)(wop + (size_t)(t + 256)*512 + dd));
  }
  float* hcur = ws + ((l & 1) ? OFF_H0 : OFF_H1);
  atomicAdd(&hcur[b*512 + t], a0);
  atomicAdd(&hcur[b*512 + 256 + t], a1);
}

// y = rmsnorm(h, n2w) -> ws[OFF_Y]
__global__ __launch_bounds__(256) void k_y(int l, const float* __restrict__ n2w, float* __restrict__ ws) {
  __shared__ float scr[256];
  int t = threadIdx.x, b = blockIdx.x;
  const float* hcur = ws + ((l & 1) ? OFF_H0 : OFF_H1);
  float h0 = hcur[b*512 + t], h1 = hcur[b*512 + 256 + t];
  float ss = blockSum256(h0*h0 + h1*h1, scr);
  float rs = rsqrtf(ss*(1.0f/512.0f) + EPS_);
  ws[OFF_Y + b*512 + t]       = h0*rs*n2w[l*512 + t];
  ws[OFF_Y + b*512 + 256 + t] = h1*rs*n2w[l*512 + 256 + t];
}

// ff1 partials: grid (fc=32, ec=8); gpart[ec][b][f] = sum over e-chunk
__global__ __launch_bounds__(256) void k_ff1(int l, const float* __restrict__ ff_w1, float* __restrict__ ws) {
  __shared__ float yT[64*68];
  __shared__ float w1T[64*68];
  int t = threadIdx.x, fc = blockIdx.x, ecb = blockIdx.y;
  for (int i = t; i < 4096; i += 256) {
    int bb = i >> 6, e = i & 63;
    yT[e*68 + bb]  = ws[OFF_Y + bb*512 + ecb*64 + e];
    w1T[e*68 + bb] = ff_w1[(size_t)l*1048576 + (size_t)(fc*64 + bb)*512 + ecb*64 + e];
  }
  __syncthreads();
  int b4 = (t & 15)*4, f4 = (t >> 4)*4;
  float acc[4][4] = {};
  for (int e = 0; e < 64; e++) {
    float4 yv = *(const float4*)(yT + e*68 + b4);
    float4 wv = *(const float4*)(w1T + e*68 + f4);
    acc[0][0] += yv.x*wv.x; acc[0][1] += yv.x*wv.y; acc[0][2] += yv.x*wv.z; acc[0][3] += yv.x*wv.w;
    acc[1][0] += yv.y*wv.x; acc[1][1] += yv.y*wv.y; acc[1][2] += yv.y*wv.z; acc[1][3] += yv.y*wv.w;
    acc[2][0] += yv.z*wv.x; acc[2][1] += yv.z*wv.y; acc[2][2] += yv.z*wv.z; acc[2][3] += yv.z*wv.w;
    acc[3][0] += yv.w*wv.x; acc[3][1] += yv.w*wv.y; acc[3][2] += yv.w*wv.z; acc[3][3] += yv.w*wv.w;
  }
  #pragma unroll
  for (int i = 0; i < 4; i++) {
    float4 v4 = make_float4(acc[i][0], acc[i][1], acc[i][2], acc[i][3]);
    *(float4*)(ws + OFF_GP + ecb*131072 + (size_t)(b4 + i)*2048 + fc*64 + f4) = v4;
  }
}

// ff2 partials: grid (dc=8, fc=32); gelu applied during staging; ffpart[fc][b][d]
__global__ __launch_bounds__(256) void k_ff2(int l, const float* __restrict__ ff_w2,
    const float* __restrict__ ff_b1, float* __restrict__ ws) {
  __shared__ float gT[64*68];
  __shared__ float w2T[64*68];
  int t = threadIdx.x, dc = blockIdx.x, fc = blockIdx.y;
  for (int i = t; i < 4096; i += 256) {
    int bb = i >> 6, f = i & 63;
    float g = ff_b1[l*2048 + fc*64 + f];
    #pragma unroll
    for (int ecb = 0; ecb < 8; ecb++)
      g += ws[OFF_GP + ecb*131072 + (size_t)bb*2048 + fc*64 + f];
    g = 0.5f*g*(1.0f + erff(g*0.70710678118654752f));  // exact gelu
    gT[f*68 + bb] = g;
    w2T[f*68 + bb] = ff_w2[(size_t)l*1048576 + (size_t)(dc*64 + bb)*2048 + fc*64 + f];
  }
  __syncthreads();
  int b4 = (t & 15)*4, d4 = (t >> 4)*4;
  float acc[4][4] = {};
  for (int f = 0; f < 64; f++) {
    float4 gv = *(const float4*)(gT + f*68 + b4);
    float4 wv = *(const float4*)(w2T + f*68 + d4);
    acc[0][0] += gv.x*wv.x; acc[0][1] += gv.x*wv.y; acc[0][2] += gv.x*wv.z; acc[0][3] += gv.x*wv.w;
    acc[1][0] += gv.y*wv.x; acc[1][1] += gv.y*wv.y; acc[1][2] += gv.y*wv.z; acc[1][3] += gv.y*wv.w;
    acc[2][0] += gv.z*wv.x; acc[2][1] += gv.z*wv.y; acc[2][2] += gv.z*wv.z; acc[2][3] += gv.z*wv.w;
    acc[3][0] += gv.w*wv.x; acc[3][1] += gv.w*wv.y; acc[3][2] += gv.w*wv.z; acc[3][3] += gv.w*wv.w;
  }
  #pragma unroll
  for (int i = 0; i < 4; i++) {
    float4 v4 = make_float4(acc[i][0], acc[i][1], acc[i][2], acc[i][3]);
    *(float4*)(ws + OFF_FP + fc*32768 + (size_t)(b4 + i)*512 + dc*64 + d4) = v4;
  }
}

// ---------------- epilogue ----------------
// grid (tt=16, b=64): new_summary shift + final x + out rmsnorm
__global__ __launch_bounds__(256) void k_fin(const float* __restrict__ summary,
    const float* __restrict__ ff_b2, const float* __restrict__ onw,
    float* __restrict__ ws, float* __restrict__ out) {
  __shared__ float scr[256];
  int t = threadIdx.x, tt = blockIdx.x, b = blockIdx.y;
  float v0, v1;
  if (tt < 15) {
    v0 = summary[b*8192 + (tt + 1)*512 + t];
    v1 = summary[b*8192 + (tt + 1)*512 + 256 + t];
  } else {
    const float* hcur = ws + OFF_H0;  // layer 5: hcur parity -> H0
    v0 = hcur[b*512 + t] + ff_b2[5*512 + t];
    v1 = hcur[b*512 + 256 + t] + ff_b2[5*512 + 256 + t];
    for (int fc = 0; fc < 32; fc++) {
      v0 += ws[OFF_FP + fc*32768 + b*512 + t];
      v1 += ws[OFF_FP + fc*32768 + b*512 + 256 + t];
    }
  }
  out[OUT_SUMM + b*8192 + tt*512 + t] = v0;
  out[OUT_SUMM + b*8192 + tt*512 + 256 + t] = v1;
  float ss = blockSum256(v0*v0 + v1*v1, scr);
  float rs = rsqrtf(ss*(1.0f/512.0f) + EPS_);
  out[b*8192 + tt*512 + t]       = v0*rs*onw[t];
  out[b*8192 + tt*512 + 256 + t] = v1*rs*onw[256 + t];
}

extern "C" void kernel_launch(void* const* d_in, const int* in_sizes, int n_in,
                              void* d_out, int out_size, void* d_ws, size_t ws_size,
                              hipStream_t stream) {
  (void)in_sizes; (void)n_in; (void)out_size; (void)ws_size;
  const float* stoch      = (const float*)d_in[0];
  const float* action     = (const float*)d_in[1];
  const float* cache      = (const float*)d_in[2];
  const float* summary    = (const float*)d_in[3];
  const float* in_w       = (const float*)d_in[4];
  const float* in_b       = (const float*)d_in[5];
  const float* in_norm_w  = (const float*)d_in[6];
  const float* n1w        = (const float*)d_in[7];
  const float* wq         = (const float*)d_in[8];
  const float* wk         = (const float*)d_in[9];
  const float* wv         = (const float*)d_in[10];
  const float* wr         = (const float*)d_in[11];
  const float* wo         = (const float*)d_in[12];
  const float* uu         = (const float*)d_in[13];
  const float* vv         = (const float*)d_in[14];
  const float* n2w        = (const float*)d_in[15];
  const float* ff_w1      = (const float*)d_in[16];
  const float* ff_b1      = (const float*)d_in[17];
  const float* ff_w2      = (const float*)d_in[18];
  const float* ff_b2      = (const float*)d_in[19];
  const float* out_norm_w = (const float*)d_in[20];
  float* out = (float*)d_out;
  float* ws  = (float*)d_ws;

  k_rel<<<2050, 256, 0, stream>>>(ws);
  k_tok<<<dim3(4, 64), 256, 0, stream>>>(stoch, action, in_w, in_b, ws);
  k_x0<<<64, 256, 0, stream>>>(in_norm_w, ws);
  for (int l = 0; l < 6; l++) {
    k_prep<<<dim3(8, 32), 256, 0, stream>>>(l, wq, wk, wr, uu, vv, n1w, ff_b2, ws, out);
    k_attn<<<dim3(8, 64), 256, 0, stream>>>(l, cache, ws, out);
    k_ctx<<<dim3(8, 64), 256, 0, stream>>>(l, wv, wo, n1w, ws);
    k_y<<<64, 256, 0, stream>>>(l, n2w, ws);
    k_ff1<<<dim3(32, 8), 256, 0, stream>>>(l, ff_w1, ws);
    k_ff2<<<dim3(8, 32), 256, 0, stream>>>(l, ff_w2, ff_b1, ws);
  }
  k_fin<<<dim3(16, 64), 256, 0, stream>>>(summary, ff_b2, out_norm_w, ws, out);
}